// Round 8
// baseline (191.120 us; speedup 1.0000x reference)
//
#include <hip/hip_runtime.h>

#define BATCH   2
#define T_LEN   2048
#define C_DIM   1024
#define NH      16
#define NKV     8
#define HD      64

typedef unsigned short u16;
typedef __attribute__((ext_vector_type(8))) short short8;
typedef __attribute__((ext_vector_type(4))) float floatx4;
typedef __attribute__((ext_vector_type(16))) float floatx16;

__device__ __forceinline__ u16 f2bf(float f) {
    union { float f; unsigned u; } v; v.f = f;
    unsigned r = v.u + 0x7FFF + ((v.u >> 16) & 1);   // round-to-nearest-even
    return (u16)(r >> 16);
}

__device__ __forceinline__ void gload_lds16(const u16* g, u16* l) {
    __builtin_amdgcn_global_load_lds(
        (const __attribute__((address_space(1))) void*)g,
        (__attribute__((address_space(3))) void*)l, 16, 0, 0);
}

// Swizzled LDS slot for (row, k-chunk cc): 8-lane read subgroups (rows R..R+7,
// fixed cc) land in 8 consecutive 16-B slots = one 128-B window = all 32 banks.
__device__ __forceinline__ int sw_idx(int row, int cc) {
    return ((row & 7) | (cc << 3) | ((row >> 3) << 5)) * 8;
}

// ---------------------------------------------------------------------------
// All fp32->bf16 conversions in ONE launch. Segments (1024-elt blocks):
// x:4096 | Wq:1024 | Wk:512 | Wv:512 | Wproj:1024 => grid 7168.
// ---------------------------------------------------------------------------
__global__ __launch_bounds__(256)
void cvt_all(const float* __restrict__ x, const float* __restrict__ Wq,
             const float* __restrict__ Wk, const float* __restrict__ Wv,
             const float* __restrict__ Wp, u16* __restrict__ xb,
             u16* __restrict__ Wqkvb, u16* __restrict__ Wpb) {
    const int blk = blockIdx.x;
    const float* src; u16* dst; long off;
    if (blk < 4096)      { src = x;  dst = xb;              off = (long)blk * 1024; }
    else if (blk < 5120) { src = Wq; dst = Wqkvb;           off = (long)(blk - 4096) * 1024; }
    else if (blk < 5632) { src = Wk; dst = Wqkvb + 1048576; off = (long)(blk - 5120) * 1024; }
    else if (blk < 6144) { src = Wv; dst = Wqkvb + 1572864; off = (long)(blk - 5632) * 1024; }
    else                 { src = Wp; dst = Wpb;             off = (long)(blk - 6144) * 1024; }
    const long i = off + (long)threadIdx.x * 4;
    const float4 f = *(const float4*)&src[i];
    ushort4 o;
    o.x = f2bf(f.x); o.y = f2bf(f.y); o.z = f2bf(f.z); o.w = f2bf(f.w);
    *(ushort4*)&dst[i] = o;
}

// ---------------------------------------------------------------------------
// Fused QKV GEMM, 32x32x16 MFMA, conflict-free swizzled LDS.
// [q|k|v](4096x2048) = xb @ Wqkvb^T. 128x128 tile, 4 waves (2x2 of 64x64).
// Epilogue: q/k -> rope+RMS+dot -> esq/esk; v -> compact bf16 vb.
// ---------------------------------------------------------------------------
__global__ __launch_bounds__(256, 4)
void gemm_qkv(const u16* __restrict__ A, const u16* __restrict__ B,
              u16* __restrict__ vb, float* __restrict__ esq,
              float* __restrict__ esk, const float* __restrict__ cosb,
              const float* __restrict__ sinb, const float* __restrict__ wb) {
    const int K = 1024;
    __shared__ u16 As[128 * 32];
    __shared__ u16 Bs[128 * 32];
    const int tid  = threadIdx.x;
    const int lane = tid & 63;
    const int wave = tid >> 6;
    const int ln31 = lane & 31;
    const int half = lane >> 5;
    const int rw   = (wave & 1) * 64;
    const int cw   = (wave >> 1) * 64;
    const int row0 = blockIdx.y * 128;
    const int col0 = blockIdx.x * 128;

    floatx16 acc[2][2] = {};   // [row-tile][col-tile]

    for (int k0 = 0; k0 < K; k0 += 32) {
        #pragma unroll
        for (int c = 0; c < 2; ++c) {
            const int l   = c * 256 + tid;
            const int row = (l & 7) | ((l >> 5) << 3);
            const int ch  = (l >> 3) & 3;
            gload_lds16(A + (size_t)(row0 + row) * K + k0 + ch * 8, &As[(size_t)l * 8]);
            gload_lds16(B + (size_t)(col0 + row) * K + k0 + ch * 8, &Bs[(size_t)l * 8]);
        }
        __syncthreads();
        #pragma unroll
        for (int kk = 0; kk < 2; ++kk) {
            const int cc = kk * 2 + half;
            const short8 a0 = *(const short8*)&As[sw_idx(rw + ln31, cc)];
            const short8 a1 = *(const short8*)&As[sw_idx(rw + 32 + ln31, cc)];
            const short8 b0 = *(const short8*)&Bs[sw_idx(cw + ln31, cc)];
            const short8 b1 = *(const short8*)&Bs[sw_idx(cw + 32 + ln31, cc)];
            acc[0][0] = __builtin_amdgcn_mfma_f32_32x32x16_bf16(a0, b0, acc[0][0], 0, 0, 0);
            acc[0][1] = __builtin_amdgcn_mfma_f32_32x32x16_bf16(a0, b1, acc[0][1], 0, 0, 0);
            acc[1][0] = __builtin_amdgcn_mfma_f32_32x32x16_bf16(a1, b0, acc[1][0], 0, 0, 0);
            acc[1][1] = __builtin_amdgcn_mfma_f32_32x32x16_bf16(a1, b1, acc[1][1], 0, 0, 0);
        }
        __syncthreads();
    }

    const int cw_g = col0 + cw;
    const int rw_g = row0 + rw;
    const int ch   = cw_g >> 6;          // head 0..31 (q:0-15 k:16-23 v:24-31)

    if (ch < 24) {      // ---- q/k: rope + RMS-norm + dot -> e^-s ----
        const float w0 = wb[ln31], w1 = wb[32 + ln31];
        #pragma unroll
        for (int ra = 0; ra < 2; ++ra)
            #pragma unroll
            for (int r = 0; r < 16; ++r) {
                const int grow = rw_g + ra * 32 + (r & 3) + 8 * (r >> 2) + 4 * half;
                const int t = grow & 2047;
                const int b = grow >> 11;
                const float c0 = cosb[t * 32 + ln31];
                const float s0 = sinb[t * 32 + ln31];
                const float x1 = acc[ra][0][r];          // d = ln31
                const float x2 = acc[ra][1][r];          // d = 32 + ln31
                const float r1 = fmaf(x1, c0,  x2 * s0);
                const float r2 = fmaf(x2, c0, -x1 * s0);
                float ss = r1 * r1 + r2 * r2;
                float dt = r1 * w0 + r2 * w1;
                #pragma unroll
                for (int m = 1; m < 32; m <<= 1) {
                    ss += __shfl_xor(ss, m, 64);
                    dt += __shfl_xor(dt, m, 64);
                }
                const float val = dt * rsqrtf(ss * (1.0f / 64.0f) + 1e-6f);
                const float e = __expf(-fminf(fmaxf(val, -44.0f), 44.0f));
                if (ln31 == 0) {
                    if (ch < 16) esq[((size_t)b * NH + ch) * T_LEN + t] = e;
                    else         esk[((size_t)b * NKV + ch - 16) * T_LEN + t] = e;
                }
            }
    } else {            // ---- v: bf16 write to compact vb (row stride 512) ----
        const int vcol = cw_g - 1536;
        #pragma unroll
        for (int ra = 0; ra < 2; ++ra)
            #pragma unroll
            for (int r = 0; r < 16; ++r) {
                const int grow = rw_g + ra * 32 + (r & 3) + 8 * (r >> 2) + 4 * half;
                vb[(size_t)grow * 512 + vcol + ln31]      = f2bf(acc[ra][0][r]);
                vb[(size_t)grow * 512 + vcol + 32 + ln31] = f2bf(acc[ra][1][r]);
            }
    }
}

// ---------------------------------------------------------------------------
// V transpose (bf16 -> bf16): vb(4096 x 512) -> Vt [b*NKV+kvh][d][T].
// ---------------------------------------------------------------------------
__global__ __launch_bounds__(256)
void vt_convert(const u16* __restrict__ vb, u16* __restrict__ Vt) {
    __shared__ u16 Lu[64][72];
    const int blk = blockIdx.x;
    const int tid = threadIdx.x;
    const int bkv = blk >> 5;            // b*NKV + kvh
    const int t0  = (blk & 31) * 64;
    const int b   = bkv >> 3;
    const int kvh = bkv & 7;
    const u16* src = vb + ((size_t)b * T_LEN + t0) * 512 + kvh * 64;
    #pragma unroll
    for (int c = 0; c < 2; ++c) {
        const int i = c * 256 + tid;
        const int s = i >> 3, d0 = (i & 7) * 8;
        *(short8*)&Lu[s][d0] = *(const short8*)&src[(size_t)s * 512 + d0];
    }
    __syncthreads();
    u16* dst = Vt + (size_t)bkv * 64 * T_LEN + t0;
    #pragma unroll
    for (int c = 0; c < 2; ++c) {
        const int i = c * 256 + tid;
        const int d = i >> 3, s0 = (i & 7) * 8;
        short8 o;
        #pragma unroll
        for (int j = 0; j < 8; ++j) o[j] = (short)Lu[s0 + j][d];
        *(short8*)&dst[(size_t)d * T_LEN + s0] = o;
    }
}

// ---------------------------------------------------------------------------
// Braid attention, MFMA 16x16x32, 512 threads = 2 s-groups x 4 row-waves.
// P = 1/(1 + esq[t]*esk[s]); no transcendentals (precomputed).
// Triangle pairing (tiles p, 31-p). fp32 LDS cross-group reduction.
// ---------------------------------------------------------------------------
__global__ __launch_bounds__(512)
void braid_attn(const float* __restrict__ esq, const float* __restrict__ esk,
                const u16* __restrict__ Vt, u16* __restrict__ yb) {
    __shared__ u16 Vd[2][4096];     // two V chunks, XOR-8 swizzled (gload layout)
    __shared__ float eskl[128];
    float* red = (float*)&Vd[0][0]; // 16 KB reduction scratch (aliased)

    const int bh   = blockIdx.y;
    const int b    = bh >> 4;
    const int h    = bh & 15;
    const int p    = blockIdx.x;    // pair 0..15
    const int tid  = threadIdx.x;
    const int lane = tid & 63;
    const int wave = tid >> 6;      // 0..7
    const int sg   = wave >> 2;     // s-group
    const int w4   = wave & 3;      // row-wave
    const int n    = lane & 15;
    const int quad = lane >> 4;
    const int row  = w4 * 16 + n;   // t-row within tile

    const float* esq_p = esq + (size_t)bh * T_LEN;
    const float* esk_p = esk + ((size_t)b * NKV + (h >> 1)) * T_LEN;
    const u16*   vt_b  = Vt + ((size_t)b * NKV + (h >> 1)) * 64 * T_LEN;
    const float  inv   = (float)(1.0 / (45.254833995939045 + 1e-6));

    for (int ph = 0; ph < 2; ++ph) {
        const int t0 = (ph ? p : (31 - p)) * 64;
        const float a = esq_p[t0 + row];
        const int send = t0 + 64;
        floatx4 acc[4] = {};

        for (int s0 = 0; s0 < send; s0 += 128) {
            __syncthreads();
            {   // stage V chunk(s): 512 threads x 16B per chunk
                const int r = tid >> 3, g = tid & 7;
                const int so = (g ^ (r & 7)) << 3;
                gload_lds16(vt_b + (size_t)r * T_LEN + s0 + so, &Vd[0][(size_t)tid * 8]);
                if (s0 + 64 < send)
                    gload_lds16(vt_b + (size_t)r * T_LEN + s0 + 64 + so, &Vd[1][(size_t)tid * 8]);
            }
            if (tid < 128 && (tid < 64 || s0 + 64 < send))
                eskl[tid] = esk_p[s0 + tid];
            __syncthreads();

            const int s0g = s0 + sg * 64;
            if (s0g < send) {
                const bool diag = (s0g == t0);
                #pragma unroll
                for (int kk = 0; kk < 2; ++kk) {
                    const float* eb = &eskl[sg * 64 + kk * 32 + quad * 8];
                    const float4 e0 = *(const float4*)eb;
                    const float4 e1 = *(const float4*)(eb + 4);
                    const float ev[8] = {e0.x, e0.y, e0.z, e0.w, e1.x, e1.y, e1.z, e1.w};
                    union { unsigned u[4]; short8 s8; } af;
                    #pragma unroll
                    for (int jj = 0; jj < 4; ++jj) {
                        float r0 = __builtin_amdgcn_rcpf(fmaf(ev[2 * jj],     a, 1.0f));
                        float r1 = __builtin_amdgcn_rcpf(fmaf(ev[2 * jj + 1], a, 1.0f));
                        if (diag) {
                            const int s_ = kk * 32 + quad * 8 + 2 * jj;
                            if (s_     > row) r0 = 0.0f;
                            if (s_ + 1 > row) r1 = 0.0f;
                        }
                        af.u[jj] = __builtin_amdgcn_perm(__float_as_uint(r1),
                                                         __float_as_uint(r0), 0x07060302u);
                    }
                    #pragma unroll
                    for (int j = 0; j < 4; ++j) {
                        const short8 bfr = *(const short8*)
                            &Vd[sg][(16 * j + n) * 64 + (((kk * 4 + quad) ^ (n & 7)) << 3)];
                        acc[j] = __builtin_amdgcn_mfma_f32_16x16x32_bf16(af.s8, bfr, acc[j], 0, 0, 0);
                    }
                }
            }
        }

        __syncthreads();
        if (sg == 1) {
            #pragma unroll
            for (int j = 0; j < 4; ++j)
                #pragma unroll
                for (int r = 0; r < 4; ++r)
                    red[(j * 4 + r) * 256 + w4 * 64 + lane] = acc[j][r];
        }
        __syncthreads();
        if (sg == 0) {
            #pragma unroll
            for (int j = 0; j < 4; ++j)
                #pragma unroll
                for (int r = 0; r < 4; ++r) {
                    const float o = acc[j][r] + red[(j * 4 + r) * 256 + w4 * 64 + lane];
                    const int t = t0 + w4 * 16 + quad * 4 + r;
                    yb[((size_t)b * T_LEN + t) * C_DIM + h * HD + 16 * j + n] = f2bf(o * inv);
                }
        }
    }
}

// ---------------------------------------------------------------------------
// Proj GEMM, 32x32x16 MFMA, 128x64 tile, conflict-free swizzled LDS.
// 4 waves as 2 (row) x 2 (col of 32); wave-tile 64x32 = 2x1 of 32x32.
// ---------------------------------------------------------------------------
__global__ __launch_bounds__(256, 4)
void gemm_proj(const u16* __restrict__ A, const u16* __restrict__ B,
               float* __restrict__ C, int M, int N, int K) {
    __shared__ u16 As[128 * 32];
    __shared__ u16 Bs[64 * 32];
    const int tid  = threadIdx.x;
    const int lane = tid & 63;
    const int wave = tid >> 6;
    const int ln31 = lane & 31;
    const int half = lane >> 5;
    const int rw   = (wave & 1) * 64;
    const int cw   = (wave >> 1) * 32;
    const int row0 = blockIdx.y * 128;
    const int col0 = blockIdx.x * 64;

    floatx16 acc[2] = {};

    for (int k0 = 0; k0 < K; k0 += 32) {
        #pragma unroll
        for (int c = 0; c < 2; ++c) {
            const int l   = c * 256 + tid;
            const int row = (l & 7) | ((l >> 5) << 3);
            const int ch  = (l >> 3) & 3;
            gload_lds16(A + (size_t)(row0 + row) * K + k0 + ch * 8, &As[(size_t)l * 8]);
        }
        {
            const int row = (tid & 7) | ((tid >> 5) << 3);   // 0..63
            const int ch  = (tid >> 3) & 3;
            gload_lds16(B + (size_t)(col0 + row) * K + k0 + ch * 8, &Bs[(size_t)tid * 8]);
        }
        __syncthreads();
        #pragma unroll
        for (int kk = 0; kk < 2; ++kk) {
            const int cc = kk * 2 + half;
            const short8 a0 = *(const short8*)&As[sw_idx(rw + ln31, cc)];
            const short8 a1 = *(const short8*)&As[sw_idx(rw + 32 + ln31, cc)];
            const short8 b0 = *(const short8*)&Bs[sw_idx(cw + ln31, cc)];
            acc[0] = __builtin_amdgcn_mfma_f32_32x32x16_bf16(a0, b0, acc[0], 0, 0, 0);
            acc[1] = __builtin_amdgcn_mfma_f32_32x32x16_bf16(a1, b0, acc[1], 0, 0, 0);
        }
        __syncthreads();
    }

    #pragma unroll
    for (int ra = 0; ra < 2; ++ra)
        #pragma unroll
        for (int r = 0; r < 16; ++r) {
            const int grow = row0 + rw + ra * 32 + (r & 3) + 8 * (r >> 2) + 4 * half;
            C[(size_t)grow * N + col0 + cw + ln31] = acc[ra][r];
        }
}

// ---------------------------------------------------------------------------
extern "C" void kernel_launch(void* const* d_in, const int* in_sizes, int n_in,
                              void* d_out, int out_size, void* d_ws, size_t ws_size,
                              hipStream_t stream) {
    const float* x     = (const float*)d_in[0];
    const float* cosb  = (const float*)d_in[1];
    const float* sinb  = (const float*)d_in[2];
    const float* Wq    = (const float*)d_in[3];
    const float* Wk    = (const float*)d_in[4];
    const float* Wv    = (const float*)d_in[5];
    const float* Wproj = (const float*)d_in[6];
    const float* wb    = (const float*)d_in[7];
    float* out = (float*)d_out;

    char* w = (char*)d_ws;
    u16* xb     = (u16*)w;  w += (size_t)4096 * 1024 * 2;
    u16* Wqkvb  = (u16*)w;  w += (size_t)2048 * 1024 * 2;   // [Wq; Wk; Wv]
    u16* Wpb    = (u16*)w;  w += (size_t)1024 * 1024 * 2;
    u16* vb     = (u16*)w;  w += (size_t)4096 * 512 * 2;    // compact v bf16
    u16* yb     = (u16*)w;  w += (size_t)4096 * 1024 * 2;
    u16* VtB    = (u16*)w;  w += (size_t)BATCH * NKV * 64 * T_LEN * 2;
    float* esq  = (float*)w; w += (size_t)BATCH * NH * T_LEN * 4;
    float* esk  = (float*)w; w += (size_t)BATCH * NKV * T_LEN * 4;

    dim3 blk(256);
    cvt_all<<<7168, blk, 0, stream>>>(x, Wq, Wk, Wv, Wproj, xb, Wqkvb, Wpb);
    gemm_qkv<<<dim3(16, 32), blk, 0, stream>>>(xb, Wqkvb, vb, esq, esk, cosb, sinb, wb);
    vt_convert<<<512, blk, 0, stream>>>(vb, VtB);
    braid_attn<<<dim3(16, 32), dim3(512), 0, stream>>>(esq, esk, VtB, yb);
    gemm_proj<<<dim3(16, 32), blk, 0, stream>>>(yb, Wpb, out, 4096, 1024, 1024);
}

// Round 9
// 165.100 us; speedup vs baseline: 1.1576x; 1.1576x over previous
//
#include <hip/hip_runtime.h>

#define BATCH   2
#define T_LEN   2048
#define C_DIM   1024
#define NH      16
#define NKV     8
#define HD      64

typedef unsigned short u16;
typedef __attribute__((ext_vector_type(8))) short short8;
typedef __attribute__((ext_vector_type(4))) float floatx4;

__device__ __forceinline__ u16 f2bf(float f) {
    union { float f; unsigned u; } v; v.f = f;
    unsigned r = v.u + 0x7FFF + ((v.u >> 16) & 1);   // round-to-nearest-even
    return (u16)(r >> 16);
}

__device__ __forceinline__ void gload_lds16(const u16* g, u16* l) {
    __builtin_amdgcn_global_load_lds(
        (const __attribute__((address_space(1))) void*)g,
        (__attribute__((address_space(3))) void*)l, 16, 0, 0);
}

// ---------------------------------------------------------------------------
// All fp32->bf16 conversions in ONE launch. Segments (1024-elt blocks):
// x:4096 | Wq:1024 | Wk:512 | Wv:512 | Wproj:1024 => grid 7168.
// ---------------------------------------------------------------------------
__global__ __launch_bounds__(256)
void cvt_all(const float* __restrict__ x, const float* __restrict__ Wq,
             const float* __restrict__ Wk, const float* __restrict__ Wv,
             const float* __restrict__ Wp, u16* __restrict__ xb,
             u16* __restrict__ Wqkvb, u16* __restrict__ Wpb) {
    const int blk = blockIdx.x;
    const float* src; u16* dst; long off;
    if (blk < 4096)      { src = x;  dst = xb;              off = (long)blk * 1024; }
    else if (blk < 5120) { src = Wq; dst = Wqkvb;           off = (long)(blk - 4096) * 1024; }
    else if (blk < 5632) { src = Wk; dst = Wqkvb + 1048576; off = (long)(blk - 5120) * 1024; }
    else if (blk < 6144) { src = Wv; dst = Wqkvb + 1572864; off = (long)(blk - 5632) * 1024; }
    else                 { src = Wp; dst = Wpb;             off = (long)(blk - 6144) * 1024; }
    const long i = off + (long)threadIdx.x * 4;
    const float4 f = *(const float4*)&src[i];
    ushort4 o;
    o.x = f2bf(f.x); o.y = f2bf(f.y); o.z = f2bf(f.z); o.w = f2bf(f.w);
    *(ushort4*)&dst[i] = o;
}

// ---------------------------------------------------------------------------
// Fused QKV GEMM, 16x16x32 MFMA (round-5 structure: 0 conflicts, coalesced
// 64B-segment staging): [q|k|v](4096x2048) = xb @ Wqkvb^T. 128x128 tile,
// 4 waves (2x2 of 64x64). 1D grid 512 with XCD swizzle: XCD k owns col-tiles
// {2k, 2k+1} -> B-slice 512KB stays resident in that XCD's 4MB L2.
// Epilogue: q/k -> rope+RMS+dot -> esq/esk; v -> compact bf16 vb.
// ---------------------------------------------------------------------------
__global__ __launch_bounds__(256)
void gemm_qkv(const u16* __restrict__ A, const u16* __restrict__ B,
              u16* __restrict__ vb, float* __restrict__ esq,
              float* __restrict__ esk, const float* __restrict__ cosb,
              const float* __restrict__ sinb, const float* __restrict__ wb) {
    const int K = 1024;
    __shared__ u16 As[128 * 32];
    __shared__ u16 Bs[128 * 32];
    const int tid    = threadIdx.x;
    const int lane   = tid & 63;
    const int wave   = tid >> 6;
    const int row_in = lane & 15;
    const int quad   = lane >> 4;
    const int koff   = quad * 8;
    const int rw     = (wave & 1) * 64;
    const int cw     = (wave >> 1) * 64;
    // XCD swizzle: dispatch-id % 8 == XCD (round-robin heuristic)
    const int bi   = blockIdx.x;         // 0..511
    const int xcd  = bi & 7;
    const int bj   = bi >> 3;            // 0..63
    const int row0 = (bj >> 1) * 128;    // 32 row-tiles
    const int col0 = (xcd * 2 + (bj & 1)) * 128;   // 16 col-tiles

    floatx4 acc[4][4] = {};

    for (int k0 = 0; k0 < K; k0 += 32) {
        #pragma unroll
        for (int c = 0; c < 2; ++c) {
            const int l  = c * 256 + tid;
            const int r  = l >> 2;
            const int kc = l & 3;
            gload_lds16(A + (size_t)(row0 + r) * K + k0 + kc * 8, &As[(size_t)l * 8]);
            gload_lds16(B + (size_t)(col0 + r) * K + k0 + kc * 8, &Bs[(size_t)l * 8]);
        }
        __syncthreads();
        short8 af[4], bf_[4];
        #pragma unroll
        for (int i = 0; i < 4; ++i)
            af[i] = *(const short8*)&As[(rw + 16 * i + row_in) * 32 + koff];
        #pragma unroll
        for (int j = 0; j < 4; ++j)
            bf_[j] = *(const short8*)&Bs[(cw + 16 * j + row_in) * 32 + koff];
        #pragma unroll
        for (int i = 0; i < 4; ++i)
            #pragma unroll
            for (int j = 0; j < 4; ++j)
                acc[i][j] = __builtin_amdgcn_mfma_f32_16x16x32_bf16(af[i], bf_[j], acc[i][j], 0, 0, 0);
        __syncthreads();
    }

    const int n    = row_in;
    const int cw_g = col0 + cw;
    const int rw_g = row0 + rw;
    const int ch   = cw_g >> 6;          // head 0..31 (q:0-15 k:16-23 v:24-31)

    if (ch < 24) {      // ---- q/k: rope + RMS-norm + dot -> e^-s ----
        const float w0 = wb[n], w1 = wb[16 + n], w2 = wb[32 + n], w3 = wb[48 + n];
        #pragma unroll
        for (int i = 0; i < 4; ++i)
            #pragma unroll
            for (int r = 0; r < 4; ++r) {
                const int grow = rw_g + 16 * i + quad * 4 + r;
                const int t = grow & 2047;
                const int b = grow >> 11;
                const float c0 = cosb[t * 32 + n];
                const float c1 = cosb[t * 32 + 16 + n];
                const float s0 = sinb[t * 32 + n];
                const float s1 = sinb[t * 32 + 16 + n];
                const float x0 = acc[i][0][r], x1 = acc[i][1][r];
                const float x2 = acc[i][2][r], x3 = acc[i][3][r];
                const float r0 = fmaf(x0, c0,  x2 * s0);
                const float r1 = fmaf(x1, c1,  x3 * s1);
                const float r2 = fmaf(x2, c0, -x0 * s0);
                const float r3 = fmaf(x3, c1, -x1 * s1);
                float ss = r0 * r0 + r1 * r1 + r2 * r2 + r3 * r3;
                float dt = r0 * w0 + r1 * w1 + r2 * w2 + r3 * w3;
                #pragma unroll
                for (int m = 1; m < 16; m <<= 1) {
                    ss += __shfl_xor(ss, m, 64);
                    dt += __shfl_xor(dt, m, 64);
                }
                const float val = dt * rsqrtf(ss * (1.0f / 64.0f) + 1e-6f);
                const float e = __expf(-fminf(fmaxf(val, -44.0f), 44.0f));
                if (n == 0) {
                    if (ch < 16) esq[((size_t)b * NH + ch) * T_LEN + t] = e;
                    else         esk[((size_t)b * NKV + ch - 16) * T_LEN + t] = e;
                }
            }
    } else {            // ---- v: bf16 write to compact vb (row stride 512) ----
        const int vcol = cw_g - 1536;
        #pragma unroll
        for (int i = 0; i < 4; ++i)
            #pragma unroll
            for (int j = 0; j < 4; ++j)
                #pragma unroll
                for (int r = 0; r < 4; ++r)
                    vb[(size_t)(rw_g + 16 * i + quad * 4 + r) * 512 + vcol + 16 * j + n]
                        = f2bf(acc[i][j][r]);
    }
}

// ---------------------------------------------------------------------------
// V transpose (bf16 -> bf16): vb(4096 x 512) -> Vt [b*NKV+kvh][d][T].
// ---------------------------------------------------------------------------
__global__ __launch_bounds__(256)
void vt_convert(const u16* __restrict__ vb, u16* __restrict__ Vt) {
    __shared__ u16 Lu[64][72];
    const int blk = blockIdx.x;
    const int tid = threadIdx.x;
    const int bkv = blk >> 5;            // b*NKV + kvh
    const int t0  = (blk & 31) * 64;
    const int b   = bkv >> 3;
    const int kvh = bkv & 7;
    const u16* src = vb + ((size_t)b * T_LEN + t0) * 512 + kvh * 64;
    #pragma unroll
    for (int c = 0; c < 2; ++c) {
        const int i = c * 256 + tid;
        const int s = i >> 3, d0 = (i & 7) * 8;
        *(short8*)&Lu[s][d0] = *(const short8*)&src[(size_t)s * 512 + d0];
    }
    __syncthreads();
    u16* dst = Vt + (size_t)bkv * 64 * T_LEN + t0;
    #pragma unroll
    for (int c = 0; c < 2; ++c) {
        const int i = c * 256 + tid;
        const int d = i >> 3, s0 = (i & 7) * 8;
        short8 o;
        #pragma unroll
        for (int j = 0; j < 8; ++j) o[j] = (short)Lu[s0 + j][d];
        *(short8*)&dst[(size_t)d * T_LEN + s0] = o;
    }
}

// ---------------------------------------------------------------------------
// Braid attention, MFMA 16x16x32, 512 threads = 2 s-groups x 4 row-waves.
// P = 1/(1 + esq[t]*esk[s]); no transcendentals (precomputed).
// Triangle pairing (tiles p, 31-p). fp32 LDS cross-group reduction.
// 1D grid 512, XCD swizzle: XCD k owns (b,kvh) groups {2k,2k+1} -> Vt slice
// 512KB resident per XCD L2.
// ---------------------------------------------------------------------------
__global__ __launch_bounds__(512)
void braid_attn(const float* __restrict__ esq, const float* __restrict__ esk,
                const u16* __restrict__ Vt, u16* __restrict__ yb) {
    __shared__ u16 Vd[2][4096];     // two V chunks, XOR-8 swizzled (gload layout)
    __shared__ float eskl[128];
    float* red = (float*)&Vd[0][0]; // 16 KB reduction scratch (aliased)

    const int bi   = blockIdx.x;    // 0..511
    const int g    = (bi & 7) * 2 + ((bi >> 8) & 1);  // (b,kvh) group 0..15
    const int wnd  = (bi >> 3) & 31;                  // 0..31 within group
    const int b    = g >> 3;
    const int kvh  = g & 7;
    const int h    = kvh * 2 + (wnd >> 4);
    const int p    = wnd & 15;      // pair 0..15
    const int bh   = b * 16 + h;
    const int tid  = threadIdx.x;
    const int lane = tid & 63;
    const int wave = tid >> 6;      // 0..7
    const int sg   = wave >> 2;     // s-group
    const int w4   = wave & 3;      // row-wave
    const int n    = lane & 15;
    const int quad = lane >> 4;
    const int row  = w4 * 16 + n;   // t-row within tile

    const float* esq_p = esq + (size_t)bh * T_LEN;
    const float* esk_p = esk + ((size_t)b * NKV + kvh) * T_LEN;
    const u16*   vt_b  = Vt + ((size_t)b * NKV + kvh) * 64 * T_LEN;
    const float  inv   = (float)(1.0 / (45.254833995939045 + 1e-6));

    for (int ph = 0; ph < 2; ++ph) {
        const int t0 = (ph ? p : (31 - p)) * 64;
        const float a = esq_p[t0 + row];
        const int send = t0 + 64;
        floatx4 acc[4] = {};

        for (int s0 = 0; s0 < send; s0 += 128) {
            __syncthreads();
            {   // stage V chunk(s): 512 threads x 16B per chunk
                const int r = tid >> 3, gg = tid & 7;
                const int so = (gg ^ (r & 7)) << 3;
                gload_lds16(vt_b + (size_t)r * T_LEN + s0 + so, &Vd[0][(size_t)tid * 8]);
                if (s0 + 64 < send)
                    gload_lds16(vt_b + (size_t)r * T_LEN + s0 + 64 + so, &Vd[1][(size_t)tid * 8]);
            }
            if (tid < 128 && (tid < 64 || s0 + 64 < send))
                eskl[tid] = esk_p[s0 + tid];
            __syncthreads();

            const int s0g = s0 + sg * 64;
            if (s0g < send) {
                const bool diag = (s0g == t0);
                #pragma unroll
                for (int kk = 0; kk < 2; ++kk) {
                    const float* eb = &eskl[sg * 64 + kk * 32 + quad * 8];
                    const float4 e0 = *(const float4*)eb;
                    const float4 e1 = *(const float4*)(eb + 4);
                    const float ev[8] = {e0.x, e0.y, e0.z, e0.w, e1.x, e1.y, e1.z, e1.w};
                    union { unsigned u[4]; short8 s8; } af;
                    #pragma unroll
                    for (int jj = 0; jj < 4; ++jj) {
                        float r0 = __builtin_amdgcn_rcpf(fmaf(ev[2 * jj],     a, 1.0f));
                        float r1 = __builtin_amdgcn_rcpf(fmaf(ev[2 * jj + 1], a, 1.0f));
                        if (diag) {
                            const int s_ = kk * 32 + quad * 8 + 2 * jj;
                            if (s_     > row) r0 = 0.0f;
                            if (s_ + 1 > row) r1 = 0.0f;
                        }
                        af.u[jj] = __builtin_amdgcn_perm(__float_as_uint(r1),
                                                         __float_as_uint(r0), 0x07060302u);
                    }
                    #pragma unroll
                    for (int j = 0; j < 4; ++j) {
                        const short8 bfr = *(const short8*)
                            &Vd[sg][(16 * j + n) * 64 + (((kk * 4 + quad) ^ (n & 7)) << 3)];
                        acc[j] = __builtin_amdgcn_mfma_f32_16x16x32_bf16(af.s8, bfr, acc[j], 0, 0, 0);
                    }
                }
            }
        }

        __syncthreads();
        if (sg == 1) {
            #pragma unroll
            for (int j = 0; j < 4; ++j)
                #pragma unroll
                for (int r = 0; r < 4; ++r)
                    red[(j * 4 + r) * 256 + w4 * 64 + lane] = acc[j][r];
        }
        __syncthreads();
        if (sg == 0) {
            #pragma unroll
            for (int j = 0; j < 4; ++j)
                #pragma unroll
                for (int r = 0; r < 4; ++r) {
                    const float o = acc[j][r] + red[(j * 4 + r) * 256 + w4 * 64 + lane];
                    const int t = t0 + w4 * 16 + quad * 4 + r;
                    yb[((size_t)b * T_LEN + t) * C_DIM + h * HD + 16 * j + n] = f2bf(o * inv);
                }
        }
    }
}

// ---------------------------------------------------------------------------
// Proj GEMM, 16x16x32 MFMA, 128x64 tile (round-5 structure), XCD swizzle.
// 4 waves as 2 (rows) x 2 (cols of 32). acc 4x2.
// ---------------------------------------------------------------------------
__global__ __launch_bounds__(256)
void gemm_proj(const u16* __restrict__ A, const u16* __restrict__ B,
               float* __restrict__ C, int M, int N, int K) {
    __shared__ u16 As[128 * 32];
    __shared__ u16 Bs[64 * 32];
    const int tid    = threadIdx.x;
    const int lane   = tid & 63;
    const int wave   = tid >> 6;
    const int row_in = lane & 15;
    const int quad   = lane >> 4;
    const int koff   = quad * 8;
    const int rw     = (wave & 1) * 64;
    const int cw     = (wave >> 1) * 32;
    const int bi   = blockIdx.x;         // 0..511
    const int xcd  = bi & 7;
    const int bj   = bi >> 3;
    const int row0 = (bj >> 1) * 128;
    const int col0 = (xcd * 2 + (bj & 1)) * 64;

    floatx4 acc[4][2] = {};

    for (int k0 = 0; k0 < K; k0 += 32) {
        #pragma unroll
        for (int c = 0; c < 2; ++c) {
            const int l  = c * 256 + tid;
            const int r  = l >> 2;
            const int kc = l & 3;
            gload_lds16(A + (size_t)(row0 + r) * K + k0 + kc * 8, &As[(size_t)l * 8]);
        }
        {
            const int r  = tid >> 2;
            const int kc = tid & 3;
            gload_lds16(B + (size_t)(col0 + r) * K + k0 + kc * 8, &Bs[(size_t)tid * 8]);
        }
        __syncthreads();
        short8 af[4], bf_[2];
        #pragma unroll
        for (int i = 0; i < 4; ++i)
            af[i] = *(const short8*)&As[(rw + 16 * i + row_in) * 32 + koff];
        #pragma unroll
        for (int j = 0; j < 2; ++j)
            bf_[j] = *(const short8*)&Bs[(cw + 16 * j + row_in) * 32 + koff];
        #pragma unroll
        for (int i = 0; i < 4; ++i)
            #pragma unroll
            for (int j = 0; j < 2; ++j)
                acc[i][j] = __builtin_amdgcn_mfma_f32_16x16x32_bf16(af[i], bf_[j], acc[i][j], 0, 0, 0);
        __syncthreads();
    }

    #pragma unroll
    for (int i = 0; i < 4; ++i)
        #pragma unroll
        for (int j = 0; j < 2; ++j)
            #pragma unroll
            for (int r = 0; r < 4; ++r)
                C[(size_t)(row0 + rw + 16 * i + quad * 4 + r) * N + col0 + cw + 16 * j + row_in]
                    = acc[i][j][r];
}

// ---------------------------------------------------------------------------
extern "C" void kernel_launch(void* const* d_in, const int* in_sizes, int n_in,
                              void* d_out, int out_size, void* d_ws, size_t ws_size,
                              hipStream_t stream) {
    const float* x     = (const float*)d_in[0];
    const float* cosb  = (const float*)d_in[1];
    const float* sinb  = (const float*)d_in[2];
    const float* Wq    = (const float*)d_in[3];
    const float* Wk    = (const float*)d_in[4];
    const float* Wv    = (const float*)d_in[5];
    const float* Wproj = (const float*)d_in[6];
    const float* wb    = (const float*)d_in[7];
    float* out = (float*)d_out;

    char* w = (char*)d_ws;
    u16* xb     = (u16*)w;  w += (size_t)4096 * 1024 * 2;
    u16* Wqkvb  = (u16*)w;  w += (size_t)2048 * 1024 * 2;   // [Wq; Wk; Wv]
    u16* Wpb    = (u16*)w;  w += (size_t)1024 * 1024 * 2;
    u16* vb     = (u16*)w;  w += (size_t)4096 * 512 * 2;    // compact v bf16
    u16* yb     = (u16*)w;  w += (size_t)4096 * 1024 * 2;
    u16* VtB    = (u16*)w;  w += (size_t)BATCH * NKV * 64 * T_LEN * 2;
    float* esq  = (float*)w; w += (size_t)BATCH * NH * T_LEN * 4;
    float* esk  = (float*)w; w += (size_t)BATCH * NKV * T_LEN * 4;

    dim3 blk(256);
    cvt_all<<<7168, blk, 0, stream>>>(x, Wq, Wk, Wv, Wproj, xb, Wqkvb, Wpb);
    gemm_qkv<<<512, blk, 0, stream>>>(xb, Wqkvb, vb, esq, esk, cosb, sinb, wb);
    vt_convert<<<512, blk, 0, stream>>>(vb, VtB);
    braid_attn<<<512, dim3(512), 0, stream>>>(esq, esk, VtB, yb);
    gemm_proj<<<512, blk, 0, stream>>>(yb, Wpb, out, 4096, 1024, 1024);
}

// Round 10
// 160.689 us; speedup vs baseline: 1.1894x; 1.0274x over previous
//
#include <hip/hip_runtime.h>

#define BATCH   2
#define T_LEN   2048
#define C_DIM   1024
#define NH      16
#define NKV     8
#define HD      64

typedef unsigned short u16;
typedef __attribute__((ext_vector_type(8))) short short8;
typedef __attribute__((ext_vector_type(4))) float floatx4;

__device__ __forceinline__ u16 f2bf(float f) {
    union { float f; unsigned u; } v; v.f = f;
    unsigned r = v.u + 0x7FFF + ((v.u >> 16) & 1);   // round-to-nearest-even
    return (u16)(r >> 16);
}

__device__ __forceinline__ void gload_lds16(const u16* g, u16* l) {
    __builtin_amdgcn_global_load_lds(
        (const __attribute__((address_space(1))) void*)g,
        (__attribute__((address_space(3))) void*)l, 16, 0, 0);
}

// ---------------------------------------------------------------------------
// All fp32->bf16 conversions in ONE launch. Segments (1024-elt blocks):
// x:4096 | Wq:1024 | Wk:512 | Wv:512 | Wproj:1024 => grid 7168.
// ---------------------------------------------------------------------------
__global__ __launch_bounds__(256)
void cvt_all(const float* __restrict__ x, const float* __restrict__ Wq,
             const float* __restrict__ Wk, const float* __restrict__ Wv,
             const float* __restrict__ Wp, u16* __restrict__ xb,
             u16* __restrict__ Wqkvb, u16* __restrict__ Wpb) {
    const int blk = blockIdx.x;
    const float* src; u16* dst; long off;
    if (blk < 4096)      { src = x;  dst = xb;              off = (long)blk * 1024; }
    else if (blk < 5120) { src = Wq; dst = Wqkvb;           off = (long)(blk - 4096) * 1024; }
    else if (blk < 5632) { src = Wk; dst = Wqkvb + 1048576; off = (long)(blk - 5120) * 1024; }
    else if (blk < 6144) { src = Wv; dst = Wqkvb + 1572864; off = (long)(blk - 5632) * 1024; }
    else                 { src = Wp; dst = Wpb;             off = (long)(blk - 6144) * 1024; }
    const long i = off + (long)threadIdx.x * 4;
    const float4 f = *(const float4*)&src[i];
    ushort4 o;
    o.x = f2bf(f.x); o.y = f2bf(f.y); o.z = f2bf(f.z); o.w = f2bf(f.w);
    *(ushort4*)&dst[i] = o;
}

// ---------------------------------------------------------------------------
// Fused QKV GEMM, 16x16x32 MFMA (round-5 structure: 0 conflicts, coalesced
// 64B-segment staging): [q|k|v](4096x2048) = xb @ Wqkvb^T. 128x128 tile,
// 4 waves (2x2 of 64x64). 1D grid 512 with XCD swizzle: XCD k owns col-tiles
// {2k, 2k+1} -> B-slice 512KB stays resident in that XCD's 4MB L2.
// Epilogue: q/k -> rope+RMS+dot -> esq/esk;
//           v  -> DIRECT transposed store to Vt[bkv][d][t] from registers
//                 (per (i,j) a lane holds 4 consecutive t at fixed d ->
//                  8-B ushort4 stores; L2 write-back merges partial lines).
// ---------------------------------------------------------------------------
__global__ __launch_bounds__(256)
void gemm_qkv(const u16* __restrict__ A, const u16* __restrict__ B,
              u16* __restrict__ Vt, float* __restrict__ esq,
              float* __restrict__ esk, const float* __restrict__ cosb,
              const float* __restrict__ sinb, const float* __restrict__ wb) {
    const int K = 1024;
    __shared__ u16 As[128 * 32];
    __shared__ u16 Bs[128 * 32];
    const int tid    = threadIdx.x;
    const int lane   = tid & 63;
    const int wave   = tid >> 6;
    const int row_in = lane & 15;
    const int quad   = lane >> 4;
    const int koff   = quad * 8;
    const int rw     = (wave & 1) * 64;
    const int cw     = (wave >> 1) * 64;
    // XCD swizzle: dispatch-id % 8 == XCD (round-robin heuristic)
    const int bi   = blockIdx.x;         // 0..511
    const int xcd  = bi & 7;
    const int bj   = bi >> 3;            // 0..63
    const int row0 = (bj >> 1) * 128;    // 32 row-tiles
    const int col0 = (xcd * 2 + (bj & 1)) * 128;   // 16 col-tiles

    floatx4 acc[4][4] = {};

    for (int k0 = 0; k0 < K; k0 += 32) {
        #pragma unroll
        for (int c = 0; c < 2; ++c) {
            const int l  = c * 256 + tid;
            const int r  = l >> 2;
            const int kc = l & 3;
            gload_lds16(A + (size_t)(row0 + r) * K + k0 + kc * 8, &As[(size_t)l * 8]);
            gload_lds16(B + (size_t)(col0 + r) * K + k0 + kc * 8, &Bs[(size_t)l * 8]);
        }
        __syncthreads();
        short8 af[4], bf_[4];
        #pragma unroll
        for (int i = 0; i < 4; ++i)
            af[i] = *(const short8*)&As[(rw + 16 * i + row_in) * 32 + koff];
        #pragma unroll
        for (int j = 0; j < 4; ++j)
            bf_[j] = *(const short8*)&Bs[(cw + 16 * j + row_in) * 32 + koff];
        #pragma unroll
        for (int i = 0; i < 4; ++i)
            #pragma unroll
            for (int j = 0; j < 4; ++j)
                acc[i][j] = __builtin_amdgcn_mfma_f32_16x16x32_bf16(af[i], bf_[j], acc[i][j], 0, 0, 0);
        __syncthreads();
    }

    const int n    = row_in;
    const int cw_g = col0 + cw;
    const int rw_g = row0 + rw;
    const int ch   = cw_g >> 6;          // head 0..31 (q:0-15 k:16-23 v:24-31)

    if (ch < 24) {      // ---- q/k: rope + RMS-norm + dot -> e^-s ----
        const float w0 = wb[n], w1 = wb[16 + n], w2 = wb[32 + n], w3 = wb[48 + n];
        #pragma unroll
        for (int i = 0; i < 4; ++i)
            #pragma unroll
            for (int r = 0; r < 4; ++r) {
                const int grow = rw_g + 16 * i + quad * 4 + r;
                const int t = grow & 2047;
                const int b = grow >> 11;
                const float c0 = cosb[t * 32 + n];
                const float c1 = cosb[t * 32 + 16 + n];
                const float s0 = sinb[t * 32 + n];
                const float s1 = sinb[t * 32 + 16 + n];
                const float x0 = acc[i][0][r], x1 = acc[i][1][r];
                const float x2 = acc[i][2][r], x3 = acc[i][3][r];
                const float r0 = fmaf(x0, c0,  x2 * s0);
                const float r1 = fmaf(x1, c1,  x3 * s1);
                const float r2 = fmaf(x2, c0, -x0 * s0);
                const float r3 = fmaf(x3, c1, -x1 * s1);
                float ss = r0 * r0 + r1 * r1 + r2 * r2 + r3 * r3;
                float dt = r0 * w0 + r1 * w1 + r2 * w2 + r3 * w3;
                #pragma unroll
                for (int m = 1; m < 16; m <<= 1) {
                    ss += __shfl_xor(ss, m, 64);
                    dt += __shfl_xor(dt, m, 64);
                }
                const float val = dt * rsqrtf(ss * (1.0f / 64.0f) + 1e-6f);
                const float e = __expf(-fminf(fmaxf(val, -44.0f), 44.0f));
                if (n == 0) {
                    if (ch < 16) esq[((size_t)b * NH + ch) * T_LEN + t] = e;
                    else         esk[((size_t)b * NKV + ch - 16) * T_LEN + t] = e;
                }
            }
    } else {            // ---- v: direct transposed register->Vt store ----
        const int vcol = cw_g - 1536;            // 0..511; this wave: vcol..vcol+63
        const int b    = rw_g >> 11;             // uniform across block (128 | 2048)
        const int tb   = (rw_g & 2047) + quad * 4;
        #pragma unroll
        for (int j = 0; j < 4; ++j) {
            const int dg  = vcol + 16 * j + n;   // global v-col 0..511
            const int kvh = dg >> 6;
            const int din = dg & 63;
            u16* dstp = Vt + ((size_t)(b * NKV + kvh) * 64 + din) * T_LEN;
            #pragma unroll
            for (int i = 0; i < 4; ++i) {
                ushort4 o;
                o.x = f2bf(acc[i][j][0]);
                o.y = f2bf(acc[i][j][1]);
                o.z = f2bf(acc[i][j][2]);
                o.w = f2bf(acc[i][j][3]);
                *(ushort4*)&dstp[tb + 16 * i] = o;
            }
        }
    }
}

// ---------------------------------------------------------------------------
// Braid attention, MFMA 16x16x32, 512 threads = 2 s-groups x 4 row-waves.
// P = 1/(1 + esq[t]*esk[s]); no transcendentals (precomputed).
// Triangle pairing (tiles p, 31-p). fp32 LDS cross-group reduction.
// 1D grid 512, XCD swizzle: XCD k owns (b,kvh) groups {2k,2k+1} -> Vt slice
// 512KB resident per XCD L2.
// ---------------------------------------------------------------------------
__global__ __launch_bounds__(512)
void braid_attn(const float* __restrict__ esq, const float* __restrict__ esk,
                const u16* __restrict__ Vt, u16* __restrict__ yb) {
    __shared__ u16 Vd[2][4096];     // two V chunks, XOR-8 swizzled (gload layout)
    __shared__ float eskl[128];
    float* red = (float*)&Vd[0][0]; // 16 KB reduction scratch (aliased)

    const int bi   = blockIdx.x;    // 0..511
    const int g    = (bi & 7) * 2 + ((bi >> 8) & 1);  // (b,kvh) group 0..15
    const int wnd  = (bi >> 3) & 31;                  // 0..31 within group
    const int b    = g >> 3;
    const int kvh  = g & 7;
    const int h    = kvh * 2 + (wnd >> 4);
    const int p    = wnd & 15;      // pair 0..15
    const int bh   = b * 16 + h;
    const int tid  = threadIdx.x;
    const int lane = tid & 63;
    const int wave = tid >> 6;      // 0..7
    const int sg   = wave >> 2;     // s-group
    const int w4   = wave & 3;      // row-wave
    const int n    = lane & 15;
    const int quad = lane >> 4;
    const int row  = w4 * 16 + n;   // t-row within tile

    const float* esq_p = esq + (size_t)bh * T_LEN;
    const float* esk_p = esk + ((size_t)b * NKV + kvh) * T_LEN;
    const u16*   vt_b  = Vt + ((size_t)b * NKV + kvh) * 64 * T_LEN;
    const float  inv   = (float)(1.0 / (45.254833995939045 + 1e-6));

    for (int ph = 0; ph < 2; ++ph) {
        const int t0 = (ph ? p : (31 - p)) * 64;
        const float a = esq_p[t0 + row];
        const int send = t0 + 64;
        floatx4 acc[4] = {};

        for (int s0 = 0; s0 < send; s0 += 128) {
            __syncthreads();
            {   // stage V chunk(s): 512 threads x 16B per chunk
                const int r = tid >> 3, gg = tid & 7;
                const int so = (gg ^ (r & 7)) << 3;
                gload_lds16(vt_b + (size_t)r * T_LEN + s0 + so, &Vd[0][(size_t)tid * 8]);
                if (s0 + 64 < send)
                    gload_lds16(vt_b + (size_t)r * T_LEN + s0 + 64 + so, &Vd[1][(size_t)tid * 8]);
            }
            if (tid < 128 && (tid < 64 || s0 + 64 < send))
                eskl[tid] = esk_p[s0 + tid];
            __syncthreads();

            const int s0g = s0 + sg * 64;
            if (s0g < send) {
                const bool diag = (s0g == t0);
                #pragma unroll
                for (int kk = 0; kk < 2; ++kk) {
                    const float* eb = &eskl[sg * 64 + kk * 32 + quad * 8];
                    const float4 e0 = *(const float4*)eb;
                    const float4 e1 = *(const float4*)(eb + 4);
                    const float ev[8] = {e0.x, e0.y, e0.z, e0.w, e1.x, e1.y, e1.z, e1.w};
                    union { unsigned u[4]; short8 s8; } af;
                    #pragma unroll
                    for (int jj = 0; jj < 4; ++jj) {
                        float r0 = __builtin_amdgcn_rcpf(fmaf(ev[2 * jj],     a, 1.0f));
                        float r1 = __builtin_amdgcn_rcpf(fmaf(ev[2 * jj + 1], a, 1.0f));
                        if (diag) {
                            const int s_ = kk * 32 + quad * 8 + 2 * jj;
                            if (s_     > row) r0 = 0.0f;
                            if (s_ + 1 > row) r1 = 0.0f;
                        }
                        af.u[jj] = __builtin_amdgcn_perm(__float_as_uint(r1),
                                                         __float_as_uint(r0), 0x07060302u);
                    }
                    #pragma unroll
                    for (int j = 0; j < 4; ++j) {
                        const short8 bfr = *(const short8*)
                            &Vd[sg][(16 * j + n) * 64 + (((kk * 4 + quad) ^ (n & 7)) << 3)];
                        acc[j] = __builtin_amdgcn_mfma_f32_16x16x32_bf16(af.s8, bfr, acc[j], 0, 0, 0);
                    }
                }
            }
        }

        __syncthreads();
        if (sg == 1) {
            #pragma unroll
            for (int j = 0; j < 4; ++j)
                #pragma unroll
                for (int r = 0; r < 4; ++r)
                    red[(j * 4 + r) * 256 + w4 * 64 + lane] = acc[j][r];
        }
        __syncthreads();
        if (sg == 0) {
            #pragma unroll
            for (int j = 0; j < 4; ++j)
                #pragma unroll
                for (int r = 0; r < 4; ++r) {
                    const float o = acc[j][r] + red[(j * 4 + r) * 256 + w4 * 64 + lane];
                    const int t = t0 + w4 * 16 + quad * 4 + r;
                    yb[((size_t)b * T_LEN + t) * C_DIM + h * HD + 16 * j + n] = f2bf(o * inv);
                }
        }
    }
}

// ---------------------------------------------------------------------------
// Proj GEMM, 16x16x32 MFMA, 128x64 tile (round-5 structure), XCD swizzle.
// 4 waves as 2 (rows) x 2 (cols of 32). acc 4x2.
// ---------------------------------------------------------------------------
__global__ __launch_bounds__(256)
void gemm_proj(const u16* __restrict__ A, const u16* __restrict__ B,
               float* __restrict__ C, int M, int N, int K) {
    __shared__ u16 As[128 * 32];
    __shared__ u16 Bs[64 * 32];
    const int tid    = threadIdx.x;
    const int lane   = tid & 63;
    const int wave   = tid >> 6;
    const int row_in = lane & 15;
    const int quad   = lane >> 4;
    const int koff   = quad * 8;
    const int rw     = (wave & 1) * 64;
    const int cw     = (wave >> 1) * 32;
    const int bi   = blockIdx.x;         // 0..511
    const int xcd  = bi & 7;
    const int bj   = bi >> 3;
    const int row0 = (bj >> 1) * 128;
    const int col0 = (xcd * 2 + (bj & 1)) * 64;

    floatx4 acc[4][2] = {};

    for (int k0 = 0; k0 < K; k0 += 32) {
        #pragma unroll
        for (int c = 0; c < 2; ++c) {
            const int l  = c * 256 + tid;
            const int r  = l >> 2;
            const int kc = l & 3;
            gload_lds16(A + (size_t)(row0 + r) * K + k0 + kc * 8, &As[(size_t)l * 8]);
        }
        {
            const int r  = tid >> 2;
            const int kc = tid & 3;
            gload_lds16(B + (size_t)(col0 + r) * K + k0 + kc * 8, &Bs[(size_t)tid * 8]);
        }
        __syncthreads();
        short8 af[4], bf_[2];
        #pragma unroll
        for (int i = 0; i < 4; ++i)
            af[i] = *(const short8*)&As[(rw + 16 * i + row_in) * 32 + koff];
        #pragma unroll
        for (int j = 0; j < 2; ++j)
            bf_[j] = *(const short8*)&Bs[(cw + 16 * j + row_in) * 32 + koff];
        #pragma unroll
        for (int i = 0; i < 4; ++i)
            #pragma unroll
            for (int j = 0; j < 2; ++j)
                acc[i][j] = __builtin_amdgcn_mfma_f32_16x16x32_bf16(af[i], bf_[j], acc[i][j], 0, 0, 0);
        __syncthreads();
    }

    #pragma unroll
    for (int i = 0; i < 4; ++i)
        #pragma unroll
        for (int j = 0; j < 2; ++j)
            #pragma unroll
            for (int r = 0; r < 4; ++r)
                C[(size_t)(row0 + rw + 16 * i + quad * 4 + r) * N + col0 + cw + 16 * j + row_in]
                    = acc[i][j][r];
}

// ---------------------------------------------------------------------------
extern "C" void kernel_launch(void* const* d_in, const int* in_sizes, int n_in,
                              void* d_out, int out_size, void* d_ws, size_t ws_size,
                              hipStream_t stream) {
    const float* x     = (const float*)d_in[0];
    const float* cosb  = (const float*)d_in[1];
    const float* sinb  = (const float*)d_in[2];
    const float* Wq    = (const float*)d_in[3];
    const float* Wk    = (const float*)d_in[4];
    const float* Wv    = (const float*)d_in[5];
    const float* Wproj = (const float*)d_in[6];
    const float* wb    = (const float*)d_in[7];
    float* out = (float*)d_out;

    char* w = (char*)d_ws;
    u16* xb     = (u16*)w;  w += (size_t)4096 * 1024 * 2;
    u16* Wqkvb  = (u16*)w;  w += (size_t)2048 * 1024 * 2;   // [Wq; Wk; Wv]
    u16* Wpb    = (u16*)w;  w += (size_t)1024 * 1024 * 2;
    u16* yb     = (u16*)w;  w += (size_t)4096 * 1024 * 2;
    u16* VtB    = (u16*)w;  w += (size_t)BATCH * NKV * 64 * T_LEN * 2;
    float* esq  = (float*)w; w += (size_t)BATCH * NH * T_LEN * 4;
    float* esk  = (float*)w; w += (size_t)BATCH * NKV * T_LEN * 4;

    dim3 blk(256);
    cvt_all<<<7168, blk, 0, stream>>>(x, Wq, Wk, Wv, Wproj, xb, Wqkvb, Wpb);
    gemm_qkv<<<512, blk, 0, stream>>>(xb, Wqkvb, VtB, esq, esk, cosb, sinb, wb);
    braid_attn<<<512, dim3(512), 0, stream>>>(esq, esk, VtB, yb);
    gemm_proj<<<512, blk, 0, stream>>>(yb, Wpb, out, 4096, 1024, 1024);
}

// Round 11
// 155.775 us; speedup vs baseline: 1.2269x; 1.0316x over previous
//
#include <hip/hip_runtime.h>

#define BATCH   2
#define T_LEN   2048
#define C_DIM   1024
#define NH      16
#define NKV     8
#define HD      64

typedef unsigned short u16;
typedef __attribute__((ext_vector_type(8))) short short8;
typedef __attribute__((ext_vector_type(4))) float floatx4;

__device__ __forceinline__ u16 f2bf(float f) {
    union { float f; unsigned u; } v; v.f = f;
    unsigned r = v.u + 0x7FFF + ((v.u >> 16) & 1);   // round-to-nearest-even
    return (u16)(r >> 16);
}

__device__ __forceinline__ void gload_lds16(const u16* g, u16* l) {
    __builtin_amdgcn_global_load_lds(
        (const __attribute__((address_space(1))) void*)g,
        (__attribute__((address_space(3))) void*)l, 16, 0, 0);
}

// ---------------------------------------------------------------------------
// All fp32->bf16 conversions in ONE launch. Segments (1024-elt blocks):
// x:4096 | Wq:1024 | Wk:512 | Wv:512 | Wproj:1024 => grid 7168.
// ---------------------------------------------------------------------------
__global__ __launch_bounds__(256)
void cvt_all(const float* __restrict__ x, const float* __restrict__ Wq,
             const float* __restrict__ Wk, const float* __restrict__ Wv,
             const float* __restrict__ Wp, u16* __restrict__ xb,
             u16* __restrict__ Wqkvb, u16* __restrict__ Wpb) {
    const int blk = blockIdx.x;
    const float* src; u16* dst; long off;
    if (blk < 4096)      { src = x;  dst = xb;              off = (long)blk * 1024; }
    else if (blk < 5120) { src = Wq; dst = Wqkvb;           off = (long)(blk - 4096) * 1024; }
    else if (blk < 5632) { src = Wk; dst = Wqkvb + 1048576; off = (long)(blk - 5120) * 1024; }
    else if (blk < 6144) { src = Wv; dst = Wqkvb + 1572864; off = (long)(blk - 5632) * 1024; }
    else                 { src = Wp; dst = Wpb;             off = (long)(blk - 6144) * 1024; }
    const long i = off + (long)threadIdx.x * 4;
    const float4 f = *(const float4*)&src[i];
    ushort4 o;
    o.x = f2bf(f.x); o.y = f2bf(f.y); o.z = f2bf(f.z); o.w = f2bf(f.w);
    *(ushort4*)&dst[i] = o;
}

// ---------------------------------------------------------------------------
// Fused QKV GEMM, 16x16x32 MFMA, BK=64 (half the barriers of BK=32; occupancy
// is grid-capped at 2 blocks/CU so 32KB LDS costs nothing). XOR-chunk staging
// swizzle (braid-validated): lane stages chunk (l&7)^(r&7) of row r=l>>3 —
// global stays 128B-run coalesced, LDS fragment reads 2-way max (free).
// [q|k|v](4096x2048) = xb @ Wqkvb^T. 128x128 tile, 4 waves (2x2 of 64x64).
// XCD swizzle: XCD k owns col-tiles {2k,2k+1} (B-slice resident in XCD L2).
// Epilogue: q/k -> rope+RMS+dot -> esq/esk; v -> direct transposed Vt store.
// ---------------------------------------------------------------------------
__global__ __launch_bounds__(256)
void gemm_qkv(const u16* __restrict__ A, const u16* __restrict__ B,
              u16* __restrict__ Vt, float* __restrict__ esq,
              float* __restrict__ esk, const float* __restrict__ cosb,
              const float* __restrict__ sinb, const float* __restrict__ wb) {
    const int K = 1024;
    __shared__ u16 As[128 * 64];   // 16 KB
    __shared__ u16 Bs[128 * 64];   // 16 KB
    const int tid    = threadIdx.x;
    const int lane   = tid & 63;
    const int wave   = tid >> 6;
    const int row_in = lane & 15;
    const int quad   = lane >> 4;
    const int rw     = (wave & 1) * 64;
    const int cw     = (wave >> 1) * 64;
    const int bi   = blockIdx.x;         // 0..511
    const int xcd  = bi & 7;
    const int bj   = bi >> 3;            // 0..63
    const int row0 = (bj >> 1) * 128;    // 32 row-tiles
    const int col0 = (xcd * 2 + (bj & 1)) * 128;   // 16 col-tiles

    floatx4 acc[4][4] = {};

    const int n    = row_in;
    const int xa   = n & 7;              // fragment-read XOR key

    for (int k0 = 0; k0 < K; k0 += 64) {
        #pragma unroll
        for (int c = 0; c < 4; ++c) {
            const int l  = c * 256 + tid;        // 0..1023
            const int r  = l >> 3;               // row 0..127
            const int kc = (l & 7) ^ (r & 7);    // swizzled 8-elem chunk
            gload_lds16(A + (size_t)(row0 + r) * K + k0 + kc * 8, &As[(size_t)l * 8]);
            gload_lds16(B + (size_t)(col0 + r) * K + k0 + kc * 8, &Bs[(size_t)l * 8]);
        }
        __syncthreads();
        #pragma unroll
        for (int kk = 0; kk < 2; ++kk) {
            const int co = ((kk * 4 + quad) ^ xa) * 8;
            short8 af[4], bf_[4];
            #pragma unroll
            for (int i = 0; i < 4; ++i)
                af[i] = *(const short8*)&As[(rw + 16 * i + n) * 64 + co];
            #pragma unroll
            for (int j = 0; j < 4; ++j)
                bf_[j] = *(const short8*)&Bs[(cw + 16 * j + n) * 64 + co];
            #pragma unroll
            for (int i = 0; i < 4; ++i)
                #pragma unroll
                for (int j = 0; j < 4; ++j)
                    acc[i][j] = __builtin_amdgcn_mfma_f32_16x16x32_bf16(af[i], bf_[j], acc[i][j], 0, 0, 0);
        }
        __syncthreads();
    }

    const int cw_g = col0 + cw;
    const int rw_g = row0 + rw;
    const int ch   = cw_g >> 6;          // head 0..31 (q:0-15 k:16-23 v:24-31)

    if (ch < 24) {      // ---- q/k: rope + RMS-norm + dot -> e^-s ----
        const float w0 = wb[n], w1 = wb[16 + n], w2 = wb[32 + n], w3 = wb[48 + n];
        #pragma unroll
        for (int i = 0; i < 4; ++i)
            #pragma unroll
            for (int r = 0; r < 4; ++r) {
                const int grow = rw_g + 16 * i + quad * 4 + r;
                const int t = grow & 2047;
                const int b = grow >> 11;
                const float c0 = cosb[t * 32 + n];
                const float c1 = cosb[t * 32 + 16 + n];
                const float s0 = sinb[t * 32 + n];
                const float s1 = sinb[t * 32 + 16 + n];
                const float x0 = acc[i][0][r], x1 = acc[i][1][r];
                const float x2 = acc[i][2][r], x3 = acc[i][3][r];
                const float r0 = fmaf(x0, c0,  x2 * s0);
                const float r1 = fmaf(x1, c1,  x3 * s1);
                const float r2 = fmaf(x2, c0, -x0 * s0);
                const float r3 = fmaf(x3, c1, -x1 * s1);
                float ss = r0 * r0 + r1 * r1 + r2 * r2 + r3 * r3;
                float dt = r0 * w0 + r1 * w1 + r2 * w2 + r3 * w3;
                #pragma unroll
                for (int m = 1; m < 16; m <<= 1) {
                    ss += __shfl_xor(ss, m, 64);
                    dt += __shfl_xor(dt, m, 64);
                }
                const float val = dt * rsqrtf(ss * (1.0f / 64.0f) + 1e-6f);
                const float e = __expf(-fminf(fmaxf(val, -44.0f), 44.0f));
                if (n == 0) {
                    if (ch < 16) esq[((size_t)b * NH + ch) * T_LEN + t] = e;
                    else         esk[((size_t)b * NKV + ch - 16) * T_LEN + t] = e;
                }
            }
    } else {            // ---- v: direct transposed register->Vt store ----
        const int vcol = cw_g - 1536;            // 0..511; this wave: vcol..vcol+63
        const int b    = rw_g >> 11;             // uniform across block
        const int tb   = (rw_g & 2047) + quad * 4;
        #pragma unroll
        for (int j = 0; j < 4; ++j) {
            const int dg  = vcol + 16 * j + n;   // global v-col 0..511
            const int kvh = dg >> 6;
            const int din = dg & 63;
            u16* dstp = Vt + ((size_t)(b * NKV + kvh) * 64 + din) * T_LEN;
            #pragma unroll
            for (int i = 0; i < 4; ++i) {
                ushort4 o;
                o.x = f2bf(acc[i][j][0]);
                o.y = f2bf(acc[i][j][1]);
                o.z = f2bf(acc[i][j][2]);
                o.w = f2bf(acc[i][j][3]);
                *(ushort4*)&dstp[tb + 16 * i] = o;
            }
        }
    }
}

// ---------------------------------------------------------------------------
// Braid attention, MFMA 16x16x32, 512 threads = 2 s-groups x 4 row-waves.
// P = 1/(1 + esq[t]*esk[s]); no transcendentals (precomputed).
// Triangle pairing (tiles p, 31-p). fp32 LDS cross-group reduction.
// XCD swizzle: XCD k owns (b,kvh) groups {2k,2k+1}.
// ---------------------------------------------------------------------------
__global__ __launch_bounds__(512)
void braid_attn(const float* __restrict__ esq, const float* __restrict__ esk,
                const u16* __restrict__ Vt, u16* __restrict__ yb) {
    __shared__ u16 Vd[2][4096];     // two V chunks, XOR-8 swizzled (gload layout)
    __shared__ float eskl[128];
    float* red = (float*)&Vd[0][0]; // 16 KB reduction scratch (aliased)

    const int bi   = blockIdx.x;    // 0..511
    const int g    = (bi & 7) * 2 + ((bi >> 8) & 1);  // (b,kvh) group 0..15
    const int wnd  = (bi >> 3) & 31;                  // 0..31 within group
    const int b    = g >> 3;
    const int kvh  = g & 7;
    const int h    = kvh * 2 + (wnd >> 4);
    const int p    = wnd & 15;      // pair 0..15
    const int bh   = b * 16 + h;
    const int tid  = threadIdx.x;
    const int lane = tid & 63;
    const int wave = tid >> 6;      // 0..7
    const int sg   = wave >> 2;     // s-group
    const int w4   = wave & 3;      // row-wave
    const int n    = lane & 15;
    const int quad = lane >> 4;
    const int row  = w4 * 16 + n;   // t-row within tile

    const float* esq_p = esq + (size_t)bh * T_LEN;
    const float* esk_p = esk + ((size_t)b * NKV + kvh) * T_LEN;
    const u16*   vt_b  = Vt + ((size_t)b * NKV + kvh) * 64 * T_LEN;
    const float  inv   = (float)(1.0 / (45.254833995939045 + 1e-6));

    for (int ph = 0; ph < 2; ++ph) {
        const int t0 = (ph ? p : (31 - p)) * 64;
        const float a = esq_p[t0 + row];
        const int send = t0 + 64;
        floatx4 acc[4] = {};

        for (int s0 = 0; s0 < send; s0 += 128) {
            __syncthreads();
            {   // stage V chunk(s): 512 threads x 16B per chunk
                const int r = tid >> 3, gg = tid & 7;
                const int so = (gg ^ (r & 7)) << 3;
                gload_lds16(vt_b + (size_t)r * T_LEN + s0 + so, &Vd[0][(size_t)tid * 8]);
                if (s0 + 64 < send)
                    gload_lds16(vt_b + (size_t)r * T_LEN + s0 + 64 + so, &Vd[1][(size_t)tid * 8]);
            }
            if (tid < 128 && (tid < 64 || s0 + 64 < send))
                eskl[tid] = esk_p[s0 + tid];
            __syncthreads();

            const int s0g = s0 + sg * 64;
            if (s0g < send) {
                const bool diag = (s0g == t0);
                #pragma unroll
                for (int kk = 0; kk < 2; ++kk) {
                    const float* eb = &eskl[sg * 64 + kk * 32 + quad * 8];
                    const float4 e0 = *(const float4*)eb;
                    const float4 e1 = *(const float4*)(eb + 4);
                    const float ev[8] = {e0.x, e0.y, e0.z, e0.w, e1.x, e1.y, e1.z, e1.w};
                    union { unsigned u[4]; short8 s8; } af;
                    #pragma unroll
                    for (int jj = 0; jj < 4; ++jj) {
                        float r0 = __builtin_amdgcn_rcpf(fmaf(ev[2 * jj],     a, 1.0f));
                        float r1 = __builtin_amdgcn_rcpf(fmaf(ev[2 * jj + 1], a, 1.0f));
                        if (diag) {
                            const int s_ = kk * 32 + quad * 8 + 2 * jj;
                            if (s_     > row) r0 = 0.0f;
                            if (s_ + 1 > row) r1 = 0.0f;
                        }
                        af.u[jj] = __builtin_amdgcn_perm(__float_as_uint(r1),
                                                         __float_as_uint(r0), 0x07060302u);
                    }
                    #pragma unroll
                    for (int j = 0; j < 4; ++j) {
                        const short8 bfr = *(const short8*)
                            &Vd[sg][(16 * j + n) * 64 + (((kk * 4 + quad) ^ (n & 7)) << 3)];
                        acc[j] = __builtin_amdgcn_mfma_f32_16x16x32_bf16(af.s8, bfr, acc[j], 0, 0, 0);
                    }
                }
            }
        }

        __syncthreads();
        if (sg == 1) {
            #pragma unroll
            for (int j = 0; j < 4; ++j)
                #pragma unroll
                for (int r = 0; r < 4; ++r)
                    red[(j * 4 + r) * 256 + w4 * 64 + lane] = acc[j][r];
        }
        __syncthreads();
        if (sg == 0) {
            #pragma unroll
            for (int j = 0; j < 4; ++j)
                #pragma unroll
                for (int r = 0; r < 4; ++r) {
                    const float o = acc[j][r] + red[(j * 4 + r) * 256 + w4 * 64 + lane];
                    const int t = t0 + w4 * 16 + quad * 4 + r;
                    yb[((size_t)b * T_LEN + t) * C_DIM + h * HD + 16 * j + n] = f2bf(o * inv);
                }
        }
    }
}

// ---------------------------------------------------------------------------
// Proj GEMM, 16x16x32 MFMA, 128x64 tile, BK=64 + XOR-chunk swizzle staging.
// 4 waves as 2 (rows) x 2 (cols of 32). acc 4x2. XCD swizzle.
// ---------------------------------------------------------------------------
__global__ __launch_bounds__(256)
void gemm_proj(const u16* __restrict__ A, const u16* __restrict__ B,
               float* __restrict__ C, int M, int N, int K) {
    __shared__ u16 As[128 * 64];   // 16 KB
    __shared__ u16 Bs[64 * 64];    //  8 KB
    const int tid    = threadIdx.x;
    const int lane   = tid & 63;
    const int wave   = tid >> 6;
    const int row_in = lane & 15;
    const int quad   = lane >> 4;
    const int rw     = (wave & 1) * 64;
    const int cw     = (wave >> 1) * 32;
    const int bi   = blockIdx.x;         // 0..511
    const int xcd  = bi & 7;
    const int bj   = bi >> 3;
    const int row0 = (bj >> 1) * 128;
    const int col0 = (xcd * 2 + (bj & 1)) * 64;

    floatx4 acc[4][2] = {};

    const int n  = row_in;
    const int xa = n & 7;

    for (int k0 = 0; k0 < K; k0 += 64) {
        #pragma unroll
        for (int c = 0; c < 4; ++c) {
            const int l  = c * 256 + tid;        // 0..1023
            const int r  = l >> 3;
            const int kc = (l & 7) ^ (r & 7);
            gload_lds16(A + (size_t)(row0 + r) * K + k0 + kc * 8, &As[(size_t)l * 8]);
        }
        #pragma unroll
        for (int c = 0; c < 2; ++c) {
            const int l  = c * 256 + tid;        // 0..511
            const int r  = l >> 3;               // 0..63
            const int kc = (l & 7) ^ (r & 7);
            gload_lds16(B + (size_t)(col0 + r) * K + k0 + kc * 8, &Bs[(size_t)l * 8]);
        }
        __syncthreads();
        #pragma unroll
        for (int kk = 0; kk < 2; ++kk) {
            const int co = ((kk * 4 + quad) ^ xa) * 8;
            short8 af[4], bf_[2];
            #pragma unroll
            for (int i = 0; i < 4; ++i)
                af[i] = *(const short8*)&As[(rw + 16 * i + n) * 64 + co];
            #pragma unroll
            for (int j = 0; j < 2; ++j)
                bf_[j] = *(const short8*)&Bs[(cw + 16 * j + n) * 64 + co];
            #pragma unroll
            for (int i = 0; i < 4; ++i)
                #pragma unroll
                for (int j = 0; j < 2; ++j)
                    acc[i][j] = __builtin_amdgcn_mfma_f32_16x16x32_bf16(af[i], bf_[j], acc[i][j], 0, 0, 0);
        }
        __syncthreads();
    }

    #pragma unroll
    for (int i = 0; i < 4; ++i)
        #pragma unroll
        for (int j = 0; j < 2; ++j)
            #pragma unroll
            for (int r = 0; r < 4; ++r)
                C[(size_t)(row0 + rw + 16 * i + quad * 4 + r) * N + col0 + cw + 16 * j + row_in]
                    = acc[i][j][r];
}

// ---------------------------------------------------------------------------
extern "C" void kernel_launch(void* const* d_in, const int* in_sizes, int n_in,
                              void* d_out, int out_size, void* d_ws, size_t ws_size,
                              hipStream_t stream) {
    const float* x     = (const float*)d_in[0];
    const float* cosb  = (const float*)d_in[1];
    const float* sinb  = (const float*)d_in[2];
    const float* Wq    = (const float*)d_in[3];
    const float* Wk    = (const float*)d_in[4];
    const float* Wv    = (const float*)d_in[5];
    const float* Wproj = (const float*)d_in[6];
    const float* wb    = (const float*)d_in[7];
    float* out = (float*)d_out;

    char* w = (char*)d_ws;
    u16* xb     = (u16*)w;  w += (size_t)4096 * 1024 * 2;
    u16* Wqkvb  = (u16*)w;  w += (size_t)2048 * 1024 * 2;   // [Wq; Wk; Wv]
    u16* Wpb    = (u16*)w;  w += (size_t)1024 * 1024 * 2;
    u16* yb     = (u16*)w;  w += (size_t)4096 * 1024 * 2;
    u16* VtB    = (u16*)w;  w += (size_t)BATCH * NKV * 64 * T_LEN * 2;
    float* esq  = (float*)w; w += (size_t)BATCH * NH * T_LEN * 4;
    float* esk  = (float*)w; w += (size_t)BATCH * NKV * T_LEN * 4;

    dim3 blk(256);
    cvt_all<<<7168, blk, 0, stream>>>(x, Wq, Wk, Wv, Wproj, xb, Wqkvb, Wpb);
    gemm_qkv<<<512, blk, 0, stream>>>(xb, Wqkvb, VtB, esq, esk, cosb, sinb, wb);
    braid_attn<<<512, dim3(512), 0, stream>>>(esq, esk, VtB, yb);
    gemm_proj<<<512, blk, 0, stream>>>(yb, Wpb, out, 4096, 1024, 1024);
}